// Round 5
// baseline (4031.134 us; speedup 1.0000x reference)
//
#include <hip/hip_runtime.h>
#include <hip/hip_bf16.h>

typedef unsigned short u16;

#define N_POL  100000
#define N_TICK 20000
#define NNODE  120000
#define NEDGE  1000000
// EMB=128, HID=256, OUT=128

static __device__ __forceinline__ float b2f(u16 u) {
    return __uint_as_float(((unsigned)u) << 16);
}
// round-to-nearest-even bf16 (finite inputs)
static __device__ __forceinline__ u16 f2b(float f) {
    unsigned u = __float_as_uint(f);
    unsigned r = (u + 0x7FFFu + ((u >> 16) & 1u)) >> 16;
    return (u16)r;
}
// dtype-agnostic input element load
static __device__ __forceinline__ float lde(const void* p, size_t i, int f32) {
    return f32 ? ((const float*)p)[i] : b2f(((const u16*)p)[i]);
}
// Runtime input-dtype detection on edge_weight (uniform [0,1)):
//  - bf16 storage: even-index u16s are bf16 values in [0,1): small, not all zero.
//  - fp32 storage, full precision: even u16s are random mantissa bits -> some huge/NaN.
//  - fp32 storage holding bf16-rounded values: even u16s ALL exactly 0.
static __device__ __forceinline__ int detect_f32(const void* ew) {
    __shared__ int s_f32;
    if (threadIdx.x == 0) {
        const u16* p = (const u16*)ew;
        int huge = 0, allz = 1;
        for (int i = 0; i < 128; i += 2) {
            u16 b = p[i];
            if (b != 0) allz = 0;
            float v = b2f(b);
            if (!(fabsf(v) <= 4.0f)) huge = 1;
        }
        s_f32 = huge | allz;
    }
    __syncthreads();
    return s_f32;
}

// ---------------- node feature build ----------------
__global__ __launch_bounds__(256) void build_pol(const void* __restrict__ pf,
                                                 const int* __restrict__ sid,
                                                 const void* __restrict__ Wp,
                                                 const void* __restrict__ bp,
                                                 const void* __restrict__ semb,
                                                 const void* __restrict__ ew,
                                                 u16* __restrict__ Xb) {
    int f32 = detect_f32(ew);
    int row = blockIdx.x * 2 + (threadIdx.x >> 7);   // grid exactly covers N_POL
    int j = threadIdx.x & 127;
    float s = lde(bp, j, f32);
#pragma unroll
    for (int k = 0; k < 7; k++)
        s = fmaf(lde(pf, (size_t)row * 7 + k, f32), lde(Wp, k * 128 + j, f32), s);
    s = fmaxf(s, 0.f);
    s += lde(semb, (size_t)sid[row] * 128 + j, f32);
    Xb[(size_t)row * 128 + j] = f2b(s);
}

__global__ __launch_bounds__(256) void build_tick(const void* __restrict__ et,
                                                  const void* __restrict__ ew,
                                                  u16* __restrict__ Xb) {
    int f32 = detect_f32(ew);
    int idx = blockIdx.x * 256 + threadIdx.x;   // grid exactly covers N_TICK*128
    Xb[(size_t)N_POL * 128 + idx] = f2b(lde(et, idx, f32));
}

// ---------------- edge scatter: agg[dst][0:128] += w * S[src][0:128] ----------------
// S: bf16 [N,128] (internal format). agg: fp32 [N,128].
__global__ __launch_bounds__(256) void scatter128(const int* __restrict__ ei,
                                                  const void* __restrict__ ew,
                                                  const u16* __restrict__ S,
                                                  float* __restrict__ agg) {
    int f32 = detect_f32(ew);
    int g = blockIdx.x * 256 + threadIdx.x;
    int e = g >> 5;                 // 32 lanes/edge * 4 elems; exact grid
    int lane = g & 31;
    int src = ei[e];
    int dst = ei[NEDGE + e];
    float w = lde(ew, e, f32);
    ushort4 xv = *(const ushort4*)(S + (size_t)src * 128 + lane * 4);
    float* ap = agg + (size_t)dst * 128 + lane * 4;
    unsafeAtomicAdd(ap + 0, b2f(xv.x) * w);
    unsafeAtomicAdd(ap + 1, b2f(xv.y) * w);
    unsafeAtomicAdd(ap + 2, b2f(xv.z) * w);
    unsafeAtomicAdd(ap + 3, b2f(xv.w) * w);
}

// ---------------- GEMM: C = [A0 fp32 | Ab bf16] @ [Wa;Wb] (+bias)(+X)(relu) ----------
// A0: [M,K0] fp32 internal. Ab: [M,KTOT-K0] bf16 internal.
// W split at row 128: rows [0,128) from Wa, rows [128,KTOT) from Wb starting at
// Wb-row wbrow (element-indexed via lde; handles input dtype).
// X (if ADDX): fp32 [M,NC] added in epilogue. FINAL: store in output dtype, else bf16.
// tile: 256 rows x 64 cols, micro 8x8, TK=16.
template<int KTOT, int K0, int NC, bool RELU, bool ADDX, bool FINAL>
__global__ __launch_bounds__(256) void gemm_k(const float* __restrict__ A0,
                                              const u16* __restrict__ Ab,
                                              const void* __restrict__ Wa,
                                              const void* __restrict__ Wb,
                                              int wbrow,
                                              const void* __restrict__ bias,
                                              const float* __restrict__ X,
                                              const void* __restrict__ ew,
                                              void* __restrict__ Cv, int M) {
    int f32 = detect_f32(ew);
    __shared__ float As[16][260];   // [k][row], +4 pad
    __shared__ float Ws[16][68];    // [k][col], +4 pad
    const int t = threadIdx.x;
    const int row0 = blockIdx.x * 256;
    const int n0 = blockIdx.y * 64;
    const int tx = t & 7;
    const int ty = t >> 3;
    float acc[8][8];
#pragma unroll
    for (int i = 0; i < 8; i++)
#pragma unroll
        for (int j = 0; j < 8; j++) acc[i][j] = 0.f;

    const int ar = t >> 2;          // 0..63
    const int akc = (t & 3) * 4;    // 0,4,8,12
    const int wk = t >> 4;          // 0..15
    const int wc = (t & 15) * 4;    // 0..60

    for (int k0 = 0; k0 < KTOT; k0 += 16) {
        // stage A tile (internal buffers, fixed formats)
#pragma unroll
        for (int i = 0; i < 4; i++) {
            int r = ar + 64 * i;
            int row = row0 + r;
            row = row < M ? row : M - 1;   // clamp; epilogue guards
            float ax, ay, az, aw;
            if (K0 > 0 && k0 < K0) {
                float4 av = *(const float4*)(A0 + (size_t)row * K0 + k0 + akc);
                ax = av.x; ay = av.y; az = av.z; aw = av.w;
            } else {
                ushort4 hv = *(const ushort4*)(Ab + (size_t)row * (KTOT - K0) + (k0 - K0) + akc);
                ax = b2f(hv.x); ay = b2f(hv.y); az = b2f(hv.z); aw = b2f(hv.w);
            }
            As[akc + 0][r] = ax;
            As[akc + 1][r] = ay;
            As[akc + 2][r] = az;
            As[akc + 3][r] = aw;
        }
        // stage W tile (input dtype via lde)
        {
            int kk = k0 + wk;
            const void* wsrc;
            size_t wb;
            if (kk < 128) { wsrc = Wa; wb = (size_t)kk * NC; }
            else          { wsrc = Wb; wb = (size_t)(kk - 128 + wbrow) * NC; }
#pragma unroll
            for (int m = 0; m < 4; m++)
                Ws[wk][wc + m] = lde(wsrc, wb + n0 + wc + m, f32);
        }
        __syncthreads();

#pragma unroll
        for (int k = 0; k < 16; k++) {
            float4 a0 = *(const float4*)&As[k][ty * 8];
            float4 a1 = *(const float4*)&As[k][ty * 8 + 4];
            float4 b0 = *(const float4*)&Ws[k][tx * 8];
            float4 b1 = *(const float4*)&Ws[k][tx * 8 + 4];
            float a[8] = {a0.x, a0.y, a0.z, a0.w, a1.x, a1.y, a1.z, a1.w};
            float b[8] = {b0.x, b0.y, b0.z, b0.w, b1.x, b1.y, b1.z, b1.w};
#pragma unroll
            for (int i = 0; i < 8; i++)
#pragma unroll
                for (int j = 0; j < 8; j++)
                    acc[i][j] = fmaf(a[i], b[j], acc[i][j]);
        }
        __syncthreads();
    }

    // epilogue
    float bv[8];
#pragma unroll
    for (int j = 0; j < 8; j++) bv[j] = lde(bias, n0 + tx * 8 + j, f32);
#pragma unroll
    for (int i = 0; i < 8; i++) {
        int row = row0 + ty * 8 + i;
        if (row < M) {
            size_t coff = (size_t)row * NC + n0 + tx * 8;
            float v[8];
#pragma unroll
            for (int j = 0; j < 8; j++) v[j] = acc[i][j] + bv[j];
            if (ADDX) {
                float4 x0 = *(const float4*)(X + coff);
                float4 x1 = *(const float4*)(X + coff + 4);
                v[0] += x0.x; v[1] += x0.y; v[2] += x0.z; v[3] += x0.w;
                v[4] += x1.x; v[5] += x1.y; v[6] += x1.z; v[7] += x1.w;
            }
            if (RELU) {
#pragma unroll
                for (int j = 0; j < 8; j++) v[j] = fmaxf(v[j], 0.f);
            }
            if (FINAL && f32) {
                float4 s0, s1;
                s0.x = v[0]; s0.y = v[1]; s0.z = v[2]; s0.w = v[3];
                s1.x = v[4]; s1.y = v[5]; s1.z = v[6]; s1.w = v[7];
                float* cp = (float*)Cv + coff;
                *(float4*)cp = s0;
                *(float4*)(cp + 4) = s1;
            } else {
                ushort4 s0, s1;
                s0.x = f2b(v[0]); s0.y = f2b(v[1]); s0.z = f2b(v[2]); s0.w = f2b(v[3]);
                s1.x = f2b(v[4]); s1.y = f2b(v[5]); s1.z = f2b(v[6]); s1.w = f2b(v[7]);
                u16* cp = (u16*)Cv + coff;
                *(ushort4*)cp = s0;
                *(ushort4*)(cp + 4) = s1;
            }
        }
    }
}

extern "C" void kernel_launch(void* const* d_in, const int* in_sizes, int n_in,
                              void* d_out, int out_size, void* d_ws, size_t ws_size,
                              hipStream_t stream) {
    const void* pf     = d_in[0];
    const int*  sid    = (const int*)d_in[1];
    const int*  ei     = (const int*)d_in[2];
    const void* ew     = d_in[3];
    const void* Wp     = d_in[4];
    const void* bp     = d_in[5];   // zeros(128) — reused as GEMM2's null bias
    const void* semb   = d_in[6];
    const void* et     = d_in[7];
    const void* W1rel  = d_in[8];
    const void* b1     = d_in[9];
    const void* W1root = d_in[10];
    const void* W2rel  = d_in[11];
    const void* b2     = d_in[12];
    const void* W2root = d_in[13];

    // Workspace: EXACTLY 122,880,000 bytes (was 184.32 MB in R2-R4 — the NaN
    // cause was reads past ws_size into foreign mapped memory).
    //   agg fp32 [N,128] @ 0        (61.44 MB)  — reused for layer1 and layer2
    //   Hb  bf16 [N,256] @ 61.44MB  (61.44 MB)
    // d_out doubles as bf16 [N,128] scratch: Xb, then T2, then final output.
    char* wsb = (char*)d_ws;
    float* agg = (float*)wsb;
    u16*   Hb  = (u16*)(wsb + (size_t)NNODE * 128 * 4);
    u16*   Xb  = (u16*)d_out;   // also T2

    // node features -> Xb (d_out)
    build_pol<<<N_POL / 2, 256, 0, stream>>>(pf, sid, Wp, bp, semb, ew, Xb);
    build_tick<<<(N_TICK * 128) / 256, 256, 0, stream>>>(et, ew, Xb);

    // layer-1 aggregation: agg = segment_sum(w * x)
    hipMemsetAsync(agg, 0, (size_t)NNODE * 128 * 4, stream);
    scatter128<<<(NEDGE * 32) / 256, 256, 0, stream>>>(ei, ew, Xb, agg);

    // h = relu([agg | x] @ [W1rel; W1root] + b1) -> Hb bf16 [N,256]
    gemm_k<256, 128, 256, true, false, false><<<dim3(469, 4), 256, 0, stream>>>(
        agg, Xb, W1rel, W1root, 0, b1, nullptr, ew, Hb, NNODE);

    // T2 = h @ W2rel -> d_out (bf16, overwrites Xb which is now dead)
    gemm_k<256, 0, 128, false, false, false><<<dim3(469, 2), 256, 0, stream>>>(
        nullptr, Hb, W2rel, W2rel, 128, bp, nullptr, ew, Xb, NNODE);

    // layer-2 aggregation on T2 (linearity: segsum(w*h) @ W2rel = segsum(w*(h@W2rel)))
    hipMemsetAsync(agg, 0, (size_t)NNODE * 128 * 4, stream);
    scatter128<<<(NEDGE * 32) / 256, 256, 0, stream>>>(ei, ew, Xb, agg);

    // out = h @ W2root + agg + b2 -> d_out (output dtype; overwrites T2, not read here)
    gemm_k<256, 0, 128, false, true, true><<<dim3(469, 2), 256, 0, stream>>>(
        nullptr, Hb, W2root, W2root, 128, b2, agg, ew, d_out, NNODE);
}

// Round 6
// 824.720 us; speedup vs baseline: 4.8879x; 4.8879x over previous
//
#include <hip/hip_runtime.h>
#include <hip/hip_bf16.h>

typedef unsigned short u16;

#define N_POL  100000
#define N_TICK 20000
#define NNODE  120000
#define NEDGE  1000000
// EMB=128, HID=256, OUT=128

static __device__ __forceinline__ float b2f(u16 u) {
    return __uint_as_float(((unsigned)u) << 16);
}
// round-to-nearest-even bf16 (finite inputs)
static __device__ __forceinline__ u16 f2b(float f) {
    unsigned u = __float_as_uint(f);
    unsigned r = (u + 0x7FFFu + ((u >> 16) & 1u)) >> 16;
    return (u16)r;
}
// dtype-agnostic input element load
static __device__ __forceinline__ float lde(const void* p, size_t i, int f32) {
    return f32 ? ((const float*)p)[i] : b2f(((const u16*)p)[i]);
}
// Runtime input-dtype detection on edge_weight (uniform [0,1)). See R4/R5 notes.
static __device__ __forceinline__ int detect_f32(const void* ew) {
    __shared__ int s_f32;
    if (threadIdx.x == 0) {
        const u16* p = (const u16*)ew;
        int huge = 0, allz = 1;
        for (int i = 0; i < 128; i += 2) {
            u16 b = p[i];
            if (b != 0) allz = 0;
            float v = b2f(b);
            if (!(fabsf(v) <= 4.0f)) huge = 1;
        }
        s_f32 = huge | allz;
    }
    __syncthreads();
    return s_f32;
}

// ---------------- node feature build ----------------
__global__ __launch_bounds__(256) void build_pol(const void* __restrict__ pf,
                                                 const int* __restrict__ sid,
                                                 const void* __restrict__ Wp,
                                                 const void* __restrict__ bp,
                                                 const void* __restrict__ semb,
                                                 const void* __restrict__ ew,
                                                 u16* __restrict__ Xb) {
    int f32 = detect_f32(ew);
    int row = blockIdx.x * 2 + (threadIdx.x >> 7);   // exact grid
    int j = threadIdx.x & 127;
    float s = lde(bp, j, f32);
#pragma unroll
    for (int k = 0; k < 7; k++)
        s = fmaf(lde(pf, (size_t)row * 7 + k, f32), lde(Wp, k * 128 + j, f32), s);
    s = fmaxf(s, 0.f);
    s += lde(semb, (size_t)sid[row] * 128 + j, f32);
    Xb[(size_t)row * 128 + j] = f2b(s);
}

__global__ __launch_bounds__(256) void build_tick(const void* __restrict__ et,
                                                  const void* __restrict__ ew,
                                                  u16* __restrict__ Xb) {
    int f32 = detect_f32(ew);
    int idx = blockIdx.x * 256 + threadIdx.x;   // exact grid
    Xb[(size_t)N_POL * 128 + idx] = f2b(lde(et, idx, f32));
}

// ---------------- CSR build (per launch; kills the f32 atomics) ----------------
__global__ __launch_bounds__(256) void hist_dst(const int* __restrict__ ei,
                                                int* __restrict__ count) {
    int e = blockIdx.x * 256 + threadIdx.x;
    if (e < NEDGE) atomicAdd(&count[ei[NEDGE + e]], 1);
}

// block-level exclusive scan (Hillis-Steele), write block sums
__global__ __launch_bounds__(256) void scan1(const int* __restrict__ count,
                                             int* __restrict__ row_tmp,
                                             int* __restrict__ bsum) {
    __shared__ int sd[256];
    int t = threadIdx.x;
    int i = blockIdx.x * 256 + t;
    int c = (i < NNODE) ? count[i] : 0;
    sd[t] = c;
    __syncthreads();
#pragma unroll
    for (int off = 1; off < 256; off <<= 1) {
        int v = (t >= off) ? sd[t - off] : 0;
        __syncthreads();
        sd[t] += v;
        __syncthreads();
    }
    if (i < NNODE) row_tmp[i] = sd[t] - c;   // exclusive
    if (t == 255) bsum[blockIdx.x] = sd[t];  // inclusive block total
}

__global__ __launch_bounds__(512) void scan2(int* __restrict__ bsum, int nb) {
    __shared__ int sd[512];
    int t = threadIdx.x;
    int v = (t < nb) ? bsum[t] : 0;
    sd[t] = v;
    __syncthreads();
#pragma unroll
    for (int off = 1; off < 512; off <<= 1) {
        int u = (t >= off) ? sd[t - off] : 0;
        __syncthreads();
        sd[t] += u;
        __syncthreads();
    }
    if (t < nb) bsum[t] = sd[t] - v;         // exclusive
}

__global__ __launch_bounds__(256) void scan3(const int* __restrict__ row_tmp,
                                             const int* __restrict__ bsum,
                                             int* __restrict__ row_start,
                                             int* __restrict__ cursor) {
    int i = blockIdx.x * 256 + threadIdx.x;
    if (i < NNODE) {
        int v = row_tmp[i] + bsum[blockIdx.x];
        row_start[i] = v;
        cursor[i] = v;
    }
    if (i == 0) row_start[NNODE] = NEDGE;
}

__global__ __launch_bounds__(256) void fill_csr(const int* __restrict__ ei,
                                                const void* __restrict__ ew,
                                                int* __restrict__ cursor,
                                                int* __restrict__ ssrc,
                                                u16* __restrict__ sw) {
    int f32 = detect_f32(ew);
    int e = blockIdx.x * 256 + threadIdx.x;
    if (e >= NEDGE) return;
    int src = ei[e];
    int dst = ei[NEDGE + e];
    int pos = atomicAdd(&cursor[dst], 1);
    ssrc[pos] = src;
    sw[pos] = f2b(lde(ew, e, f32));
}

// ---------------- gather-aggregate: agg[n] = sum_{e in seg(n)} w_e * S[src_e] ------
// S: bf16 [N,128]. agg: bf16 [N,128]. One wave per node, 2 channels/lane, f32 acc.
__global__ __launch_bounds__(256) void gather128(const int* __restrict__ row_start,
                                                 const int* __restrict__ ssrc,
                                                 const u16* __restrict__ sw,
                                                 const u16* __restrict__ S,
                                                 u16* __restrict__ agg) {
    int n = blockIdx.x * 4 + (threadIdx.x >> 6);   // exact: 30000*4 = 120000
    int lane = threadIdx.x & 63;
    int s0 = row_start[n], s1 = row_start[n + 1];
    float a0 = 0.f, a1 = 0.f;
    int e = s0;
    for (; e + 4 <= s1; e += 4) {
        float w[4]; ushort2 xv[4];
#pragma unroll
        for (int u = 0; u < 4; u++) {
            int sr = ssrc[e + u];
            w[u] = b2f(sw[e + u]);
            xv[u] = *(const ushort2*)(S + (size_t)sr * 128 + lane * 2);
        }
#pragma unroll
        for (int u = 0; u < 4; u++) {
            a0 = fmaf(b2f(xv[u].x), w[u], a0);
            a1 = fmaf(b2f(xv[u].y), w[u], a1);
        }
    }
    for (; e < s1; e++) {
        int sr = ssrc[e];
        float w = b2f(sw[e]);
        ushort2 xv = *(const ushort2*)(S + (size_t)sr * 128 + lane * 2);
        a0 = fmaf(b2f(xv.x), w, a0);
        a1 = fmaf(b2f(xv.y), w, a1);
    }
    ushort2 o;
    o.x = f2b(a0);
    o.y = f2b(a1);
    *(ushort2*)(agg + (size_t)n * 128 + lane * 2) = o;
}

// ---------------- GEMM: C = [A0 | Ab] @ [Wa;Wb] (+bias)(+X)(relu) ----------------
// A0: [M,K0] (fp32 if A0F32 else bf16). Ab: [M,KTOT-K0] bf16.
// W rows [0,128) from Wa, [128,KTOT) from Wb starting at row wbrow (input dtype).
// X (if ADDX): bf16 [M,NC] added in epilogue. FINAL: store output dtype, else bf16.
template<int KTOT, int K0, int NC, bool A0F32, bool RELU, bool ADDX, bool FINAL>
__global__ __launch_bounds__(256) void gemm_k(const void* __restrict__ A0,
                                              const u16* __restrict__ Ab,
                                              const void* __restrict__ Wa,
                                              const void* __restrict__ Wb,
                                              int wbrow,
                                              const void* __restrict__ bias,
                                              const u16* __restrict__ X,
                                              const void* __restrict__ ew,
                                              void* __restrict__ Cv, int M) {
    int f32 = detect_f32(ew);
    __shared__ float As[16][260];
    __shared__ float Ws[16][68];
    const int t = threadIdx.x;
    const int row0 = blockIdx.x * 256;
    const int n0 = blockIdx.y * 64;
    const int tx = t & 7;
    const int ty = t >> 3;
    float acc[8][8];
#pragma unroll
    for (int i = 0; i < 8; i++)
#pragma unroll
        for (int j = 0; j < 8; j++) acc[i][j] = 0.f;

    const int ar = t >> 2;
    const int akc = (t & 3) * 4;
    const int wk = t >> 4;
    const int wc = (t & 15) * 4;

    for (int k0 = 0; k0 < KTOT; k0 += 16) {
#pragma unroll
        for (int i = 0; i < 4; i++) {
            int r = ar + 64 * i;
            int row = row0 + r;
            row = row < M ? row : M - 1;
            float ax, ay, az, aw;
            if (K0 > 0 && k0 < K0) {
                if (A0F32) {
                    float4 av = *(const float4*)((const float*)A0 + (size_t)row * K0 + k0 + akc);
                    ax = av.x; ay = av.y; az = av.z; aw = av.w;
                } else {
                    ushort4 hv = *(const ushort4*)((const u16*)A0 + (size_t)row * K0 + k0 + akc);
                    ax = b2f(hv.x); ay = b2f(hv.y); az = b2f(hv.z); aw = b2f(hv.w);
                }
            } else {
                ushort4 hv = *(const ushort4*)(Ab + (size_t)row * (KTOT - K0) + (k0 - K0) + akc);
                ax = b2f(hv.x); ay = b2f(hv.y); az = b2f(hv.z); aw = b2f(hv.w);
            }
            As[akc + 0][r] = ax;
            As[akc + 1][r] = ay;
            As[akc + 2][r] = az;
            As[akc + 3][r] = aw;
        }
        {
            int kk = k0 + wk;
            const void* wsrc;
            size_t wb;
            if (kk < 128) { wsrc = Wa; wb = (size_t)kk * NC; }
            else          { wsrc = Wb; wb = (size_t)(kk - 128 + wbrow) * NC; }
#pragma unroll
            for (int m = 0; m < 4; m++)
                Ws[wk][wc + m] = lde(wsrc, wb + n0 + wc + m, f32);
        }
        __syncthreads();

#pragma unroll
        for (int k = 0; k < 16; k++) {
            float4 a0 = *(const float4*)&As[k][ty * 8];
            float4 a1 = *(const float4*)&As[k][ty * 8 + 4];
            float4 b0 = *(const float4*)&Ws[k][tx * 8];
            float4 b1 = *(const float4*)&Ws[k][tx * 8 + 4];
            float a[8] = {a0.x, a0.y, a0.z, a0.w, a1.x, a1.y, a1.z, a1.w};
            float b[8] = {b0.x, b0.y, b0.z, b0.w, b1.x, b1.y, b1.z, b1.w};
#pragma unroll
            for (int i = 0; i < 8; i++)
#pragma unroll
                for (int j = 0; j < 8; j++)
                    acc[i][j] = fmaf(a[i], b[j], acc[i][j]);
        }
        __syncthreads();
    }

    float bv[8];
#pragma unroll
    for (int j = 0; j < 8; j++) bv[j] = lde(bias, n0 + tx * 8 + j, f32);
#pragma unroll
    for (int i = 0; i < 8; i++) {
        int row = row0 + ty * 8 + i;
        if (row < M) {
            size_t coff = (size_t)row * NC + n0 + tx * 8;
            float v[8];
#pragma unroll
            for (int j = 0; j < 8; j++) v[j] = acc[i][j] + bv[j];
            if (ADDX) {
                ushort4 x0 = *(const ushort4*)(X + coff);
                ushort4 x1 = *(const ushort4*)(X + coff + 4);
                v[0] += b2f(x0.x); v[1] += b2f(x0.y); v[2] += b2f(x0.z); v[3] += b2f(x0.w);
                v[4] += b2f(x1.x); v[5] += b2f(x1.y); v[6] += b2f(x1.z); v[7] += b2f(x1.w);
            }
            if (RELU) {
#pragma unroll
                for (int j = 0; j < 8; j++) v[j] = fmaxf(v[j], 0.f);
            }
            if (FINAL && f32) {
                float4 s0, s1;
                s0.x = v[0]; s0.y = v[1]; s0.z = v[2]; s0.w = v[3];
                s1.x = v[4]; s1.y = v[5]; s1.z = v[6]; s1.w = v[7];
                float* cp = (float*)Cv + coff;
                *(float4*)cp = s0;
                *(float4*)(cp + 4) = s1;
            } else {
                ushort4 s0, s1;
                s0.x = f2b(v[0]); s0.y = f2b(v[1]); s0.z = f2b(v[2]); s0.w = f2b(v[3]);
                s1.x = f2b(v[4]); s1.y = f2b(v[5]); s1.z = f2b(v[6]); s1.w = f2b(v[7]);
                u16* cp = (u16*)Cv + coff;
                *(ushort4*)cp = s0;
                *(ushort4*)(cp + 4) = s1;
            }
        }
    }
}

extern "C" void kernel_launch(void* const* d_in, const int* in_sizes, int n_in,
                              void* d_out, int out_size, void* d_ws, size_t ws_size,
                              hipStream_t stream) {
    const void* pf     = d_in[0];
    const int*  sid    = (const int*)d_in[1];
    const int*  ei     = (const int*)d_in[2];
    const void* ew     = d_in[3];
    const void* Wp     = d_in[4];
    const void* bp     = d_in[5];   // zeros(128) — null bias for T2 GEMM
    const void* semb   = d_in[6];
    const void* et     = d_in[7];
    const void* W1rel  = d_in[8];
    const void* b1     = d_in[9];
    const void* W1root = d_in[10];
    const void* W2rel  = d_in[11];
    const void* b2     = d_in[12];
    const void* W2root = d_in[13];

    // Workspace (~100.1 MB, within the proven 122.88 MB budget):
    char* w = (char*)d_ws;
    u16*  agg       = (u16*)w;                          // bf16 [N,128]  30,720,000
    u16*  Hb        = (u16*)(w + 30720000);             // bf16 [N,256]  61,440,000
    int*  ssrc      = (int*)(w + 92160000);             // int  [E]       4,000,000
    u16*  sw        = (u16*)(w + 96160000);             // bf16 [E]       2,000,000
    int*  row_start = (int*)(w + 98160000);             // int  [N+1]       480,008
    int*  row_tmp   = (int*)(w + 98640008);             // int  [N]         480,000
    int*  cursor    = (int*)(w + 99120008);             // int  [N]         480,000
    int*  count     = (int*)(w + 99600008);             // int  [N]         480,000
    int*  bsum      = (int*)(w + 100080008);            // int  [512]         2,048
    u16*  Xb        = (u16*)d_out;                      // bf16 [N,128]; also T2

    const int EB = (NEDGE + 255) / 256;   // 3907
    const int NB = (NNODE + 255) / 256;   // 469

    // CSR build (once; reused by both gathers)
    hipMemsetAsync(count, 0, NNODE * sizeof(int), stream);
    hist_dst<<<EB, 256, 0, stream>>>(ei, count);
    scan1<<<NB, 256, 0, stream>>>(count, row_tmp, bsum);
    scan2<<<1, 512, 0, stream>>>(bsum, NB);
    scan3<<<NB, 256, 0, stream>>>(row_tmp, bsum, row_start, cursor);
    fill_csr<<<EB, 256, 0, stream>>>(ei, ew, cursor, ssrc, sw);

    // node features -> Xb (d_out)
    build_pol<<<N_POL / 2, 256, 0, stream>>>(pf, sid, Wp, bp, semb, ew, Xb);
    build_tick<<<(N_TICK * 128) / 256, 256, 0, stream>>>(et, ew, Xb);

    // layer-1 aggregation: agg = segment_sum(w * x)   [gather, no atomics]
    gather128<<<NNODE / 4, 256, 0, stream>>>(row_start, ssrc, sw, Xb, agg);

    // h = relu([agg | x] @ [W1rel; W1root] + b1) -> Hb bf16 [N,256]
    gemm_k<256, 128, 256, false, true, false, false><<<dim3(NB, 4), 256, 0, stream>>>(
        agg, Xb, W1rel, W1root, 0, b1, nullptr, ew, Hb, NNODE);

    // T2 = h @ W2rel -> d_out bf16 (overwrites Xb, now dead)
    gemm_k<256, 0, 128, false, false, false, false><<<dim3(NB, 2), 256, 0, stream>>>(
        nullptr, Hb, W2rel, W2rel, 128, bp, nullptr, ew, Xb, NNODE);

    // layer-2 aggregation on T2 (linearity): agg = segment_sum(w * T2)
    gather128<<<NNODE / 4, 256, 0, stream>>>(row_start, ssrc, sw, Xb, agg);

    // out = h @ W2root + agg + b2 -> d_out (output dtype)
    gemm_k<256, 0, 128, false, false, true, true><<<dim3(NB, 2), 256, 0, stream>>>(
        nullptr, Hb, W2root, W2root, 128, b2, agg, ew, d_out, NNODE);
}

// Round 7
// 583.535 us; speedup vs baseline: 6.9081x; 1.4133x over previous
//
#include <hip/hip_runtime.h>
#include <hip/hip_bf16.h>

typedef unsigned short u16;
using short8  = __attribute__((ext_vector_type(8))) short;
using float4v = __attribute__((ext_vector_type(4))) float;

#define N_POL  100000
#define N_TICK 20000
#define NNODE  120000
#define NEDGE  1000000
// EMB=128, HID=256, OUT=128

static __device__ __forceinline__ float b2f(u16 u) {
    return __uint_as_float(((unsigned)u) << 16);
}
static __device__ __forceinline__ u16 f2b(float f) {
    unsigned u = __float_as_uint(f);
    unsigned r = (u + 0x7FFFu + ((u >> 16) & 1u)) >> 16;
    return (u16)r;
}
static __device__ __forceinline__ float lde(const void* p, size_t i, int f32) {
    return f32 ? ((const float*)p)[i] : b2f(((const u16*)p)[i]);
}
// Runtime input-dtype detection on edge_weight (uniform [0,1)). See R4/R5 notes.
static __device__ __forceinline__ int detect_f32(const void* ew) {
    __shared__ int s_f32;
    if (threadIdx.x == 0) {
        const u16* p = (const u16*)ew;
        int huge = 0, allz = 1;
        for (int i = 0; i < 128; i += 2) {
            u16 b = p[i];
            if (b != 0) allz = 0;
            float v = b2f(b);
            if (!(fabsf(v) <= 4.0f)) huge = 1;
        }
        s_f32 = huge | allz;
    }
    __syncthreads();
    return s_f32;
}

// MFMA B-fragment address: element (k,n) of a [256,Ntot] matrix ->
// frag index ((n/16)*8 + k/32)*512 + (((k>>3)&3)*16 + (n&15))*8 + (k&7)
static __device__ __forceinline__ size_t frag_addr(int k, int n) {
    return ((size_t)((n >> 4) * 8 + (k >> 5)) * 64 + (((k >> 3) & 3) * 16 + (n & 15))) * 8
           + (k & 7);
}

// ---------------- node feature build ----------------
__global__ __launch_bounds__(256) void build_pol(const void* __restrict__ pf,
                                                 const int* __restrict__ sid,
                                                 const void* __restrict__ Wp,
                                                 const void* __restrict__ bp,
                                                 const void* __restrict__ semb,
                                                 const void* __restrict__ ew,
                                                 u16* __restrict__ Xb) {
    int f32 = detect_f32(ew);
    int row = blockIdx.x * 2 + (threadIdx.x >> 7);
    int j = threadIdx.x & 127;
    float s = lde(bp, j, f32);
#pragma unroll
    for (int k = 0; k < 7; k++)
        s = fmaf(lde(pf, (size_t)row * 7 + k, f32), lde(Wp, k * 128 + j, f32), s);
    s = fmaxf(s, 0.f);
    s += lde(semb, (size_t)sid[row] * 128 + j, f32);
    Xb[(size_t)row * 128 + j] = f2b(s);
}

__global__ __launch_bounds__(256) void build_tick(const void* __restrict__ et,
                                                  const void* __restrict__ ew,
                                                  u16* __restrict__ Xb) {
    int f32 = detect_f32(ew);
    int idx = blockIdx.x * 256 + threadIdx.x;
    Xb[(size_t)N_POL * 128 + idx] = f2b(lde(et, idx, f32));
}

// ---------------- weight fragment prep (once per launch; B is tiny) ----------------
// GEMM1 B[k][n], k in [0,256): k<128 -> W1rel[k][n], else W1root[k-128][n]; N=256.
__global__ __launch_bounds__(256) void prep_wf1(const void* __restrict__ W1rel,
                                                const void* __restrict__ W1root,
                                                const void* __restrict__ ew,
                                                u16* __restrict__ Wf) {
    int f32 = detect_f32(ew);
    int idx = blockIdx.x * 256 + threadIdx.x;   // 65536
    int k = idx >> 8, n = idx & 255;
    float v = (k < 128) ? lde(W1rel, (size_t)k * 256 + n, f32)
                        : lde(W1root, (size_t)(k - 128) * 256 + n, f32);
    Wf[frag_addr(k, n)] = f2b(v);
}

// GEMM23 B[k][n], k in [0,256): n<128 -> W2rel[k][n], else W2root[k][n-128]; N=256.
__global__ __launch_bounds__(256) void prep_wf2(const void* __restrict__ W2rel,
                                                const void* __restrict__ W2root,
                                                const void* __restrict__ ew,
                                                u16* __restrict__ Wf) {
    int f32 = detect_f32(ew);
    int idx = blockIdx.x * 256 + threadIdx.x;   // 65536
    int k = idx >> 8, n = idx & 255;
    float v = (n < 128) ? lde(W2rel, (size_t)k * 128 + n, f32)
                        : lde(W2root, (size_t)k * 128 + (n - 128), f32);
    Wf[frag_addr(k, n)] = f2b(v);
}

// ---------------- CSR build ----------------
__global__ __launch_bounds__(256) void hist_dst(const int* __restrict__ ei,
                                                int* __restrict__ count) {
    int e = blockIdx.x * 256 + threadIdx.x;
    if (e < NEDGE) atomicAdd(&count[ei[NEDGE + e]], 1);
}

__global__ __launch_bounds__(256) void scan1(const int* __restrict__ count,
                                             int* __restrict__ row_tmp,
                                             int* __restrict__ bsum) {
    __shared__ int sd[256];
    int t = threadIdx.x;
    int i = blockIdx.x * 256 + t;
    int c = (i < NNODE) ? count[i] : 0;
    sd[t] = c;
    __syncthreads();
#pragma unroll
    for (int off = 1; off < 256; off <<= 1) {
        int v = (t >= off) ? sd[t - off] : 0;
        __syncthreads();
        sd[t] += v;
        __syncthreads();
    }
    if (i < NNODE) row_tmp[i] = sd[t] - c;
    if (t == 255) bsum[blockIdx.x] = sd[t];
}

__global__ __launch_bounds__(512) void scan2(int* __restrict__ bsum, int nb) {
    __shared__ int sd[512];
    int t = threadIdx.x;
    int v = (t < nb) ? bsum[t] : 0;
    sd[t] = v;
    __syncthreads();
#pragma unroll
    for (int off = 1; off < 512; off <<= 1) {
        int u = (t >= off) ? sd[t - off] : 0;
        __syncthreads();
        sd[t] += u;
        __syncthreads();
    }
    if (t < nb) bsum[t] = sd[t] - v;
}

__global__ __launch_bounds__(256) void scan3(const int* __restrict__ row_tmp,
                                             const int* __restrict__ bsum,
                                             int* __restrict__ row_start,
                                             int* __restrict__ cursor) {
    int i = blockIdx.x * 256 + threadIdx.x;
    if (i < NNODE) {
        int v = row_tmp[i] + bsum[blockIdx.x];
        row_start[i] = v;
        cursor[i] = v;
    }
    if (i == 0) row_start[NNODE] = NEDGE;
}

__global__ __launch_bounds__(256) void fill_csr(const int* __restrict__ ei,
                                                const void* __restrict__ ew,
                                                int* __restrict__ cursor,
                                                int* __restrict__ ssrc,
                                                u16* __restrict__ sw) {
    int f32 = detect_f32(ew);
    int e = blockIdx.x * 256 + threadIdx.x;
    if (e >= NEDGE) return;
    int src = ei[e];
    int dst = ei[NEDGE + e];
    int pos = atomicAdd(&cursor[dst], 1);
    ssrc[pos] = src;
    sw[pos] = f2b(lde(ew, e, f32));
}

// ---------------- gather-aggregate: agg[n] = sum_e w_e * S[src_e], pitch 128 ------
__global__ __launch_bounds__(256) void gather128(const int* __restrict__ row_start,
                                                 const int* __restrict__ ssrc,
                                                 const u16* __restrict__ sw,
                                                 const u16* __restrict__ S,
                                                 u16* __restrict__ agg) {
    int n = blockIdx.x * 4 + (threadIdx.x >> 6);
    int lane = threadIdx.x & 63;
    int s0 = row_start[n], s1 = row_start[n + 1];
    float a0 = 0.f, a1 = 0.f;
    int e = s0;
    for (; e + 4 <= s1; e += 4) {
        float w[4]; ushort2 xv[4];
#pragma unroll
        for (int u = 0; u < 4; u++) {
            int sr = ssrc[e + u];
            w[u] = b2f(sw[e + u]);
            xv[u] = *(const ushort2*)(S + (size_t)sr * 128 + lane * 2);
        }
#pragma unroll
        for (int u = 0; u < 4; u++) {
            a0 = fmaf(b2f(xv[u].x), w[u], a0);
            a1 = fmaf(b2f(xv[u].y), w[u], a1);
        }
    }
    for (; e < s1; e++) {
        int sr = ssrc[e];
        float w = b2f(sw[e]);
        ushort2 xv = *(const ushort2*)(S + (size_t)sr * 128 + lane * 2);
        a0 = fmaf(b2f(xv.x), w, a0);
        a1 = fmaf(b2f(xv.y), w, a1);
    }
    ushort2 o;
    o.x = f2b(a0);
    o.y = f2b(a1);
    *(ushort2*)(agg + (size_t)n * 128 + lane * 2) = o;
}

// ---------------- MFMA GEMM: C = [A0(cols 0:128) | Ab(cols 128:256)] @ Wf -----------
// A0/Ab: bf16, row pitches PA0/PA1. Wf: pre-packed B fragments, K=256, N=256.
// Block: 128 rows x 128 cols (grid.y selects col half). 4 waves 2x2, wave = 64x64.
// SPLIT=0: out1[row*OP1 + n] for all n, bias = bias1[n], RELU optional.
// SPLIT=1: n<128 -> out1 (no bias); n>=128 -> out2[row*OP2 + n-128] + bias2[n-128].
template<bool RELU, bool SPLIT>
__global__ __launch_bounds__(256) void mfma_gemm(const u16* __restrict__ A0, int PA0,
                                                 const u16* __restrict__ Ab, int PA1,
                                                 const u16* __restrict__ Wf,
                                                 const void* __restrict__ bias1,
                                                 const void* __restrict__ bias2,
                                                 u16* __restrict__ out1, int OP1,
                                                 u16* __restrict__ out2, int OP2,
                                                 const void* __restrict__ ew, int M) {
    int f32 = detect_f32(ew);
    const int row0 = blockIdx.x * 128;
    const int n0 = blockIdx.y * 128;
    const int wid = threadIdx.x >> 6;
    const int lane = threadIdx.x & 63;
    const int wy = wid >> 1, wx = wid & 1;
    const int mw = row0 + wy * 64;          // wave row base
    const int nw = n0 + wx * 64;            // wave col base
    const int q = lane >> 4, lm = lane & 15;

    float4v acc[4][4];
#pragma unroll
    for (int i = 0; i < 4; i++)
#pragma unroll
        for (int j = 0; j < 4; j++) acc[i][j] = (float4v){0.f, 0.f, 0.f, 0.f};

#pragma unroll
    for (int kb = 0; kb < 8; kb++) {
        const u16* abase = (kb < 4) ? (A0 + kb * 32) : (Ab + (kb - 4) * 32);
        const int pitch = (kb < 4) ? PA0 : PA1;
        short8 a[4], b[4];
#pragma unroll
        for (int ti = 0; ti < 4; ti++) {
            int r = mw + ti * 16 + lm;
            r = r < M ? r : M - 1;
            a[ti] = *(const short8*)(abase + (size_t)r * pitch + q * 8);
        }
#pragma unroll
        for (int tj = 0; tj < 4; tj++) {
            int nt = ((nw + tj * 16) >> 4);
            b[tj] = *(const short8*)(Wf + ((size_t)(nt * 8 + kb) * 64 + lane) * 8);
        }
#pragma unroll
        for (int ti = 0; ti < 4; ti++)
#pragma unroll
            for (int tj = 0; tj < 4; tj++)
                acc[ti][tj] = __builtin_amdgcn_mfma_f32_16x16x32_bf16(a[ti], b[tj],
                                                                      acc[ti][tj], 0, 0, 0);
    }

    // epilogue: C/D layout col = lane&15, row = q*4 + reg
#pragma unroll
    for (int tj = 0; tj < 4; tj++) {
        int n_g = nw + tj * 16 + lm;
        float bv;
        u16* dst;
        int dpitch;
        if (!SPLIT) {
            bv = lde(bias1, n_g, f32);
            dst = out1 + n_g;
            dpitch = OP1;
        } else if (n_g < 128) {
            bv = 0.f;
            dst = out1 + n_g;
            dpitch = OP1;
        } else {
            bv = lde(bias2, n_g - 128, f32);
            dst = out2 + (n_g - 128);
            dpitch = OP2;
        }
#pragma unroll
        for (int ti = 0; ti < 4; ti++) {
            int rbase = mw + ti * 16 + q * 4;
#pragma unroll
            for (int r = 0; r < 4; r++) {
                int row = rbase + r;
                if (row < M) {
                    float v = acc[ti][tj][r] + bv;
                    if (RELU) v = fmaxf(v, 0.f);
                    dst[(size_t)row * dpitch] = f2b(v);
                }
            }
        }
    }
}

// ---------------- final add: out = P + agg2 (output dtype) ----------------
__global__ __launch_bounds__(256) void add_out(const u16* __restrict__ P,
                                               const u16* __restrict__ agg2,
                                               const void* __restrict__ ew,
                                               void* __restrict__ out) {
    int f32 = detect_f32(ew);
    size_t i = ((size_t)blockIdx.x * 256 + threadIdx.x) * 4;   // exact: 15.36M/4
    ushort4 pv = *(const ushort4*)(P + i);
    ushort4 av = *(const ushort4*)(agg2 + i);
    float v0 = b2f(pv.x) + b2f(av.x);
    float v1 = b2f(pv.y) + b2f(av.y);
    float v2 = b2f(pv.z) + b2f(av.z);
    float v3 = b2f(pv.w) + b2f(av.w);
    if (f32) {
        float4 s; s.x = v0; s.y = v1; s.z = v2; s.w = v3;
        *(float4*)((float*)out + i) = s;
    } else {
        ushort4 s; s.x = f2b(v0); s.y = f2b(v1); s.z = f2b(v2); s.w = f2b(v3);
        *(ushort4*)((u16*)out + i) = s;
    }
}

extern "C" void kernel_launch(void* const* d_in, const int* in_sizes, int n_in,
                              void* d_out, int out_size, void* d_ws, size_t ws_size,
                              hipStream_t stream) {
    const void* pf     = d_in[0];
    const int*  sid    = (const int*)d_in[1];
    const int*  ei     = (const int*)d_in[2];
    const void* ew     = d_in[3];
    const void* Wp     = d_in[4];
    const void* bp     = d_in[5];
    const void* semb   = d_in[6];
    const void* et     = d_in[7];
    const void* W1rel  = d_in[8];
    const void* b1     = d_in[9];
    const void* W1root = d_in[10];
    const void* W2rel  = d_in[11];
    const void* b2     = d_in[12];
    const void* W2root = d_in[13];

    // Workspace (~100.3 MB < proven 122.88 MB budget):
    char* w = (char*)d_ws;
    u16* agg       = (u16*)w;                    // bf16 [N,128]; later P lives here
    u16* Hb        = (u16*)(w + 30720000);       // bf16 [N,256]; later agg2 (pitch 128)
    u16* Wf1       = (u16*)(w + 92160000);       // 131072 B
    u16* Wf2       = (u16*)(w + 92291072);       // 131072 B
    int* ssrc      = (int*)(w + 92422144);       // int [E]
    u16* sw        = (u16*)(w + 96422144);       // bf16 [E]
    int* row_start = (int*)(w + 98422144);       // int [N+1]
    int* row_tmp   = (int*)(w + 98902148);
    int* cursor    = (int*)(w + 99382148);
    int* count     = (int*)(w + 99862148);
    int* bsum      = (int*)(w + 100342148);
    u16* Xb        = (u16*)d_out;                // bf16 [N,128]; later T2
    u16* P         = agg;                        // bf16 [N,128] (after GEMM1)
    u16* agg2      = Hb;                         // bf16 [N,128] (after GEMM23)

    const int EB = (NEDGE + 255) / 256;   // 3907
    const int NB = (NNODE + 255) / 256;   // 469
    const int MB = (NNODE + 127) / 128;   // 938

    // CSR build (reused by both gathers)
    hipMemsetAsync(count, 0, NNODE * sizeof(int), stream);
    hist_dst<<<EB, 256, 0, stream>>>(ei, count);
    scan1<<<NB, 256, 0, stream>>>(count, row_tmp, bsum);
    scan2<<<1, 512, 0, stream>>>(bsum, NB);
    scan3<<<NB, 256, 0, stream>>>(row_tmp, bsum, row_start, cursor);
    fill_csr<<<EB, 256, 0, stream>>>(ei, ew, cursor, ssrc, sw);

    // weight fragments
    prep_wf1<<<256, 256, 0, stream>>>(W1rel, W1root, ew, Wf1);
    prep_wf2<<<256, 256, 0, stream>>>(W2rel, W2root, ew, Wf2);

    // node features -> Xb (d_out)
    build_pol<<<N_POL / 2, 256, 0, stream>>>(pf, sid, Wp, bp, semb, ew, Xb);
    build_tick<<<(N_TICK * 128) / 256, 256, 0, stream>>>(et, ew, Xb);

    // layer-1 aggregation
    gather128<<<NNODE / 4, 256, 0, stream>>>(row_start, ssrc, sw, Xb, agg);

    // h = relu([agg | x] @ [W1rel;W1root] + b1) -> Hb [N,256]
    mfma_gemm<true, false><<<dim3(MB, 2), 256, 0, stream>>>(
        agg, 128, Xb, 128, Wf1, b1, nullptr, Hb, 256, nullptr, 0, ew, NNODE);

    // [T2 | P] = Hb @ [W2rel | W2root(+b2)] ; T2 -> d_out (Xb dead), P -> agg region
    mfma_gemm<false, true><<<dim3(MB, 2), 256, 0, stream>>>(
        Hb, 256, Hb + 128, 256, Wf2, nullptr, b2, Xb, 128, P, 128, ew, NNODE);

    // layer-2 aggregation on T2 -> agg2 (Hb region; Hb dead)
    gather128<<<NNODE / 4, 256, 0, stream>>>(row_start, ssrc, sw, Xb, agg2);

    // out = P + agg2 -> d_out (T2 dead)
    add_out<<<(NNODE * 128) / 1024, 256, 0, stream>>>(P, agg2, ew, d_out);
}

// Round 8
// 574.905 us; speedup vs baseline: 7.0118x; 1.0150x over previous
//
#include <hip/hip_runtime.h>
#include <hip/hip_bf16.h>

typedef unsigned short u16;
using short8  = __attribute__((ext_vector_type(8))) short;
using float4v = __attribute__((ext_vector_type(4))) float;

#define N_POL  100000
#define N_TICK 20000
#define NNODE  120000
#define NEDGE  1000000
// EMB=128, HID=256, OUT=128

static __device__ __forceinline__ float b2f(u16 u) {
    return __uint_as_float(((unsigned)u) << 16);
}
static __device__ __forceinline__ u16 f2b(float f) {
    unsigned u = __float_as_uint(f);
    unsigned r = (u + 0x7FFFu + ((u >> 16) & 1u)) >> 16;
    return (u16)r;
}
static __device__ __forceinline__ float lde(const void* p, size_t i, int f32) {
    return f32 ? ((const float*)p)[i] : b2f(((const u16*)p)[i]);
}
// Runtime input-dtype detection on edge_weight (uniform [0,1)). See R4/R5 notes.
static __device__ __forceinline__ int detect_f32(const void* ew) {
    __shared__ int s_f32;
    if (threadIdx.x == 0) {
        const u16* p = (const u16*)ew;
        int huge = 0, allz = 1;
        for (int i = 0; i < 128; i += 2) {
            u16 b = p[i];
            if (b != 0) allz = 0;
            float v = b2f(b);
            if (!(fabsf(v) <= 4.0f)) huge = 1;
        }
        s_f32 = huge | allz;
    }
    __syncthreads();
    return s_f32;
}

// MFMA B-fragment address for K=256, N=256 packed weights (verified R7):
// element (k,n) -> ((n/16)*8 + k/32)*512 + (((k>>3)&3)*16 + (n&15))*8 + (k&7)
static __device__ __forceinline__ size_t frag_addr(int k, int n) {
    return ((size_t)((n >> 4) * 8 + (k >> 5)) * 64 + (((k >> 3) & 3) * 16 + (n & 15))) * 8
           + (k & 7);
}

// ---------------- node feature build ----------------
__global__ __launch_bounds__(256) void build_pol(const void* __restrict__ pf,
                                                 const int* __restrict__ sid,
                                                 const void* __restrict__ Wp,
                                                 const void* __restrict__ bp,
                                                 const void* __restrict__ semb,
                                                 const void* __restrict__ ew,
                                                 u16* __restrict__ Xb) {
    int f32 = detect_f32(ew);
    int row = blockIdx.x * 2 + (threadIdx.x >> 7);
    int j = threadIdx.x & 127;
    float s = lde(bp, j, f32);
#pragma unroll
    for (int k = 0; k < 7; k++)
        s = fmaf(lde(pf, (size_t)row * 7 + k, f32), lde(Wp, k * 128 + j, f32), s);
    s = fmaxf(s, 0.f);
    s += lde(semb, (size_t)sid[row] * 128 + j, f32);
    Xb[(size_t)row * 128 + j] = f2b(s);
}

__global__ __launch_bounds__(256) void build_tick(const void* __restrict__ et,
                                                  const void* __restrict__ ew,
                                                  u16* __restrict__ Xb) {
    int f32 = detect_f32(ew);
    int idx = blockIdx.x * 256 + threadIdx.x;
    Xb[(size_t)N_POL * 128 + idx] = f2b(lde(et, idx, f32));
}

// ---------------- weight fragment prep ----------------
// GEMM1 B[k][n]: k<128 -> W1rel[k][n], else W1root[k-128][n]; N=256.
__global__ __launch_bounds__(256) void prep_wf1(const void* __restrict__ W1rel,
                                                const void* __restrict__ W1root,
                                                const void* __restrict__ ew,
                                                u16* __restrict__ Wf) {
    int f32 = detect_f32(ew);
    int idx = blockIdx.x * 256 + threadIdx.x;   // 65536
    int k = idx >> 8, n = idx & 255;
    float v = (k < 128) ? lde(W1rel, (size_t)k * 256 + n, f32)
                        : lde(W1root, (size_t)(k - 128) * 256 + n, f32);
    Wf[frag_addr(k, n)] = f2b(v);
}

// GEMM2 B[k][n]: n<128 -> W2rel[k][n], else W2root[k][n-128]; N=256.
__global__ __launch_bounds__(256) void prep_wf2(const void* __restrict__ W2rel,
                                                const void* __restrict__ W2root,
                                                const void* __restrict__ ew,
                                                u16* __restrict__ Wf) {
    int f32 = detect_f32(ew);
    int idx = blockIdx.x * 256 + threadIdx.x;   // 65536
    int k = idx >> 8, n = idx & 255;
    float v = (n < 128) ? lde(W2rel, (size_t)k * 128 + n, f32)
                        : lde(W2root, (size_t)k * 128 + (n - 128), f32);
    Wf[frag_addr(k, n)] = f2b(v);
}

// ---------------- CSR build ----------------
__global__ __launch_bounds__(256) void hist_dst(const int* __restrict__ ei,
                                                int* __restrict__ count) {
    int e = blockIdx.x * 256 + threadIdx.x;
    if (e < NEDGE) atomicAdd(&count[ei[NEDGE + e]], 1);
}

__global__ __launch_bounds__(256) void scan1(const int* __restrict__ count,
                                             int* __restrict__ row_tmp,
                                             int* __restrict__ bsum) {
    __shared__ int sd[256];
    int t = threadIdx.x;
    int i = blockIdx.x * 256 + t;
    int c = (i < NNODE) ? count[i] : 0;
    sd[t] = c;
    __syncthreads();
#pragma unroll
    for (int off = 1; off < 256; off <<= 1) {
        int v = (t >= off) ? sd[t - off] : 0;
        __syncthreads();
        sd[t] += v;
        __syncthreads();
    }
    if (i < NNODE) row_tmp[i] = sd[t] - c;
    if (t == 255) bsum[blockIdx.x] = sd[t];
}

__global__ __launch_bounds__(512) void scan2(int* __restrict__ bsum, int nb) {
    __shared__ int sd[512];
    int t = threadIdx.x;
    int v = (t < nb) ? bsum[t] : 0;
    sd[t] = v;
    __syncthreads();
#pragma unroll
    for (int off = 1; off < 512; off <<= 1) {
        int u = (t >= off) ? sd[t - off] : 0;
        __syncthreads();
        sd[t] += u;
        __syncthreads();
    }
    if (t < nb) bsum[t] = sd[t] - v;
}

__global__ __launch_bounds__(256) void scan3(const int* __restrict__ row_tmp,
                                             const int* __restrict__ bsum,
                                             int* __restrict__ row_start,
                                             int* __restrict__ cursor) {
    int i = blockIdx.x * 256 + threadIdx.x;
    if (i < NNODE) {
        int v = row_tmp[i] + bsum[blockIdx.x];
        row_start[i] = v;
        cursor[i] = v;
    }
    if (i == 0) row_start[NNODE] = NEDGE;
}

__global__ __launch_bounds__(256) void fill_csr(const int* __restrict__ ei,
                                                const void* __restrict__ ew,
                                                int* __restrict__ cursor,
                                                int* __restrict__ ssrc,
                                                u16* __restrict__ sw) {
    int f32 = detect_f32(ew);
    int e = blockIdx.x * 256 + threadIdx.x;
    if (e >= NEDGE) return;
    int src = ei[e];
    int dst = ei[NEDGE + e];
    int pos = atomicAdd(&cursor[dst], 1);
    ssrc[pos] = src;
    sw[pos] = f2b(lde(ew, e, f32));
}

// ---------------- gather1: agg[n] = sum_e w_e * S[src_e]  (bf16 out, pitch 128) ----
__global__ __launch_bounds__(256) void gather128(const int* __restrict__ row_start,
                                                 const int* __restrict__ ssrc,
                                                 const u16* __restrict__ sw,
                                                 const u16* __restrict__ S,
                                                 u16* __restrict__ agg) {
    int n = blockIdx.x * 4 + (threadIdx.x >> 6);
    int lane = threadIdx.x & 63;
    int s0 = row_start[n], s1 = row_start[n + 1];
    float a0 = 0.f, a1 = 0.f;
    int e = s0;
    for (; e + 8 <= s1; e += 8) {
        float w[8]; ushort2 xv[8];
#pragma unroll
        for (int u = 0; u < 8; u++) {
            int sr = ssrc[e + u];
            w[u] = b2f(sw[e + u]);
            xv[u] = *(const ushort2*)(S + (size_t)sr * 128 + lane * 2);
        }
#pragma unroll
        for (int u = 0; u < 8; u++) {
            a0 = fmaf(b2f(xv[u].x), w[u], a0);
            a1 = fmaf(b2f(xv[u].y), w[u], a1);
        }
    }
    for (; e < s1; e++) {
        int sr = ssrc[e];
        float w = b2f(sw[e]);
        ushort2 xv = *(const ushort2*)(S + (size_t)sr * 128 + lane * 2);
        a0 = fmaf(b2f(xv.x), w, a0);
        a1 = fmaf(b2f(xv.y), w, a1);
    }
    ushort2 o;
    o.x = f2b(a0);
    o.y = f2b(a1);
    *(ushort2*)(agg + (size_t)n * 128 + lane * 2) = o;
}

// ---------------- gather2 + add P: out[n] = P[n] + sum_e w_e * T2[src_e] ----------
__global__ __launch_bounds__(256) void gather_add(const int* __restrict__ row_start,
                                                  const int* __restrict__ ssrc,
                                                  const u16* __restrict__ sw,
                                                  const u16* __restrict__ T2,
                                                  const u16* __restrict__ P,
                                                  const void* __restrict__ ew,
                                                  void* __restrict__ out) {
    int f32 = detect_f32(ew);
    int n = blockIdx.x * 4 + (threadIdx.x >> 6);
    int lane = threadIdx.x & 63;
    int s0 = row_start[n], s1 = row_start[n + 1];
    float a0 = 0.f, a1 = 0.f;
    int e = s0;
    for (; e + 8 <= s1; e += 8) {
        float w[8]; ushort2 xv[8];
#pragma unroll
        for (int u = 0; u < 8; u++) {
            int sr = ssrc[e + u];
            w[u] = b2f(sw[e + u]);
            xv[u] = *(const ushort2*)(T2 + (size_t)sr * 128 + lane * 2);
        }
#pragma unroll
        for (int u = 0; u < 8; u++) {
            a0 = fmaf(b2f(xv[u].x), w[u], a0);
            a1 = fmaf(b2f(xv[u].y), w[u], a1);
        }
    }
    for (; e < s1; e++) {
        int sr = ssrc[e];
        float w = b2f(sw[e]);
        ushort2 xv = *(const ushort2*)(T2 + (size_t)sr * 128 + lane * 2);
        a0 = fmaf(b2f(xv.x), w, a0);
        a1 = fmaf(b2f(xv.y), w, a1);
    }
    ushort2 pv = *(const ushort2*)(P + (size_t)n * 128 + lane * 2);
    float v0 = a0 + b2f(pv.x);
    float v1 = a1 + b2f(pv.y);
    if (f32) {
        float2 s; s.x = v0; s.y = v1;
        *(float2*)((float*)out + (size_t)n * 128 + lane * 2) = s;
    } else {
        ushort2 s; s.x = f2b(v0); s.y = f2b(v1);
        *(ushort2*)((u16*)out + (size_t)n * 128 + lane * 2) = s;
    }
}

// ---------------- fused dual MFMA GEMM ----------------
// Phase 1: H = relu([agg|Xb] @ Wf1 + b1)   (64 rows x 256 cols) -> LDS
// Phase 2: [T2 | P] = H @ Wf2 (+b2 on P half)  -> global
// Block 256 thr (4 waves 2x2: wy=row-half, wx=col-half). Wave tile 32r x 128c (2 h-halves of 64c).
// LDS layout = phase-2 A-frag order: element (row,k) at u16 index ((k>>3)*64 + row)*8 + (k&7).
__global__ __launch_bounds__(256) void fused_gemm(const u16* __restrict__ agg,
                                                  const u16* __restrict__ Xb,
                                                  const u16* __restrict__ Wf1,
                                                  const u16* __restrict__ Wf2,
                                                  const void* __restrict__ b1,
                                                  const void* __restrict__ b2,
                                                  u16* __restrict__ T2,
                                                  u16* __restrict__ P,
                                                  const void* __restrict__ ew, int M) {
    int f32 = detect_f32(ew);
    __shared__ u16 LDSH[32 * 64 * 8];   // 32 KB
    const int row0 = blockIdx.x * 64;
    const int wid = threadIdx.x >> 6;
    const int lane = threadIdx.x & 63;
    const int wy = wid >> 1, wx = wid & 1;
    const int q = lane >> 4, lm = lane & 15;
    const int rw = wy * 32;             // wave row base (block-local)

    // ---- phase 1 ----
#pragma unroll
    for (int h = 0; h < 2; h++) {
        float4v acc[2][4];
#pragma unroll
        for (int i = 0; i < 2; i++)
#pragma unroll
            for (int j = 0; j < 4; j++) acc[i][j] = (float4v){0.f, 0.f, 0.f, 0.f};
#pragma unroll
        for (int kb = 0; kb < 8; kb++) {
            const u16* abase = (kb < 4) ? (agg + kb * 32) : (Xb + (kb - 4) * 32);
            short8 a[2], b[4];
#pragma unroll
            for (int ti = 0; ti < 2; ti++) {
                int r = row0 + rw + ti * 16 + lm;
                r = r < M ? r : M - 1;
                a[ti] = *(const short8*)(abase + (size_t)r * 128 + q * 8);
            }
#pragma unroll
            for (int tj = 0; tj < 4; tj++) {
                int nt = wx * 8 + h * 4 + tj;
                b[tj] = *(const short8*)(Wf1 + ((size_t)(nt * 8 + kb) * 64 + lane) * 8);
            }
#pragma unroll
            for (int ti = 0; ti < 2; ti++)
#pragma unroll
                for (int tj = 0; tj < 4; tj++)
                    acc[ti][tj] = __builtin_amdgcn_mfma_f32_16x16x32_bf16(a[ti], b[tj],
                                                                          acc[ti][tj], 0, 0, 0);
        }
        // bias + relu -> LDS (phase-2 A-frag order)
#pragma unroll
        for (int tj = 0; tj < 4; tj++) {
            int col = wx * 128 + (h * 4 + tj) * 16 + lm;
            float bv = lde(b1, col, f32);
            int kq = col >> 3, jj = col & 7;
#pragma unroll
            for (int ti = 0; ti < 2; ti++) {
                int rl = rw + ti * 16 + q * 4;
#pragma unroll
                for (int r = 0; r < 4; r++) {
                    float v = fmaxf(acc[ti][tj][r] + bv, 0.f);
                    LDSH[((size_t)kq * 64 + rl + r) * 8 + jj] = f2b(v);
                }
            }
        }
    }
    __syncthreads();

    // ---- phase 2 ----
#pragma unroll
    for (int h = 0; h < 2; h++) {
        float4v acc[2][4];
#pragma unroll
        for (int i = 0; i < 2; i++)
#pragma unroll
            for (int j = 0; j < 4; j++) acc[i][j] = (float4v){0.f, 0.f, 0.f, 0.f};
#pragma unroll
        for (int kb = 0; kb < 8; kb++) {
            short8 a[2], b[4];
#pragma unroll
            for (int ti = 0; ti < 2; ti++) {
                int rl = rw + ti * 16 + lm;
                a[ti] = *(const short8*)(LDSH + ((size_t)(kb * 4 + q) * 64 + rl) * 8);
            }
#pragma unroll
            for (int tj = 0; tj < 4; tj++) {
                int nt = wx * 8 + h * 4 + tj;
                b[tj] = *(const short8*)(Wf2 + ((size_t)(nt * 8 + kb) * 64 + lane) * 8);
            }
#pragma unroll
            for (int ti = 0; ti < 2; ti++)
#pragma unroll
                for (int tj = 0; tj < 4; tj++)
                    acc[ti][tj] = __builtin_amdgcn_mfma_f32_16x16x32_bf16(a[ti], b[tj],
                                                                          acc[ti][tj], 0, 0, 0);
        }
        // epilogue: cols <128 -> T2 (no bias), >=128 -> P (+b2)
#pragma unroll
        for (int tj = 0; tj < 4; tj++) {
            int n_g = wx * 128 + (h * 4 + tj) * 16 + lm;
            float bv;
            u16* dst;
            if (n_g < 128) {
                bv = 0.f;
                dst = T2 + n_g;
            } else {
                bv = lde(b2, n_g - 128, f32);
                dst = P + (n_g - 128);
            }
#pragma unroll
            for (int ti = 0; ti < 2; ti++) {
                int rbase = row0 + rw + ti * 16 + q * 4;
#pragma unroll
                for (int r = 0; r < 4; r++) {
                    int row = rbase + r;
                    if (row < M)
                        dst[(size_t)row * 128] = f2b(acc[ti][tj][r] + bv);
                }
            }
        }
    }
}

extern "C" void kernel_launch(void* const* d_in, const int* in_sizes, int n_in,
                              void* d_out, int out_size, void* d_ws, size_t ws_size,
                              hipStream_t stream) {
    const void* pf     = d_in[0];
    const int*  sid    = (const int*)d_in[1];
    const int*  ei     = (const int*)d_in[2];
    const void* ew     = d_in[3];
    const void* Wp     = d_in[4];
    const void* bp     = d_in[5];
    const void* semb   = d_in[6];
    const void* et     = d_in[7];
    const void* W1rel  = d_in[8];
    const void* b1     = d_in[9];
    const void* W1root = d_in[10];
    const void* W2rel  = d_in[11];
    const void* b2     = d_in[12];
    const void* W2root = d_in[13];

    // Workspace (~100.3 MB < proven 122.88 MB budget):
    char* w = (char*)d_ws;
    u16* agg       = (u16*)w;                    // bf16 [N,128]
    u16* T2        = (u16*)(w + 30720000);       // bf16 [N,128]
    u16* P         = (u16*)(w + 61440000);       // bf16 [N,128]
    u16* Wf1       = (u16*)(w + 92160000);       // 131072 B
    u16* Wf2       = (u16*)(w + 92291072);       // 131072 B
    int* ssrc      = (int*)(w + 92422144);       // int [E]
    u16* sw        = (u16*)(w + 96422144);       // bf16 [E]
    int* row_start = (int*)(w + 98422144);       // int [N+1]
    int* row_tmp   = (int*)(w + 98902148);
    int* cursor    = (int*)(w + 99382148);
    int* count     = (int*)(w + 99862148);
    int* bsum      = (int*)(w + 100342148);
    u16* Xb        = (u16*)d_out;                // bf16 [N,128] scratch until fused_gemm done

    const int EB = (NEDGE + 255) / 256;   // 3907
    const int NB = (NNODE + 255) / 256;   // 469
    const int GB = (NNODE + 63) / 64;     // 1875

    // CSR build (reused by both gathers)
    hipMemsetAsync(count, 0, NNODE * sizeof(int), stream);
    hist_dst<<<EB, 256, 0, stream>>>(ei, count);
    scan1<<<NB, 256, 0, stream>>>(count, row_tmp, bsum);
    scan2<<<1, 512, 0, stream>>>(bsum, NB);
    scan3<<<NB, 256, 0, stream>>>(row_tmp, bsum, row_start, cursor);
    fill_csr<<<EB, 256, 0, stream>>>(ei, ew, cursor, ssrc, sw);

    // weight fragments
    prep_wf1<<<256, 256, 0, stream>>>(W1rel, W1root, ew, Wf1);
    prep_wf2<<<256, 256, 0, stream>>>(W2rel, W2root, ew, Wf2);

    // node features -> Xb (d_out)
    build_pol<<<N_POL / 2, 256, 0, stream>>>(pf, sid, Wp, bp, semb, ew, Xb);
    build_tick<<<(N_TICK * 128) / 256, 256, 0, stream>>>(et, ew, Xb);

    // layer-1 aggregation
    gather128<<<NNODE / 4, 256, 0, stream>>>(row_start, ssrc, sw, Xb, agg);

    // fused: H = relu([agg|Xb]@Wf1+b1) in LDS; [T2|P] = H@Wf2 (+b2 on P)
    fused_gemm<<<GB, 256, 0, stream>>>(agg, Xb, Wf1, Wf2, b1, b2, T2, P, ew, NNODE);

    // out = P + segment_sum(w * T2)   (d_out scratch Xb is dead now)
    gather_add<<<NNODE / 4, 256, 0, stream>>>(row_start, ssrc, sw, T2, P, ew, d_out);
}